// Round 1
// baseline (14740.889 us; speedup 1.0000x reference)
//
#include <hip/hip_runtime.h>
#include <hip/hip_bf16.h>
#include <math.h>

#define NT    2048      // B*S rows
#define S_LEN 1024
#define NH    12
#define DM    768
#define DKH   64
#define FF    3072
#define NL    12
#define VOC   50257

__device__ __forceinline__ float gelu_f(float x) {
    // exact gelu: 0.5*x*(1+erf(x/sqrt(2)))
    return 0.5f * x * (1.0f + erff(x * 0.70710678118654752f));
}

// ---------------- embedding: x = tok_emb[ids] + pe ----------------
__global__ void __launch_bounds__(256) embed_kernel(const int* __restrict__ ids,
        const float* __restrict__ tok, const float* __restrict__ pe,
        float* __restrict__ x) {
    int i   = blockIdx.x * 256 + threadIdx.x;   // < NT*DM
    int row = i / DM;
    int c   = i - row * DM;
    int s   = row & (S_LEN - 1);
    x[i] = tok[(size_t)ids[row] * DM + c] + pe[(size_t)s * DM + c];
}

// ---------------- fp32 register-tiled GEMM ----------------
// C[M,N] = A[M,K] @ B[K,N] (+bias) (+gelu).  M % BM == 0, K % 16 == 0 assumed.
template<int BM, int BN, int TM, int TN>
__device__ __forceinline__ void gemm_body(const float* __restrict__ A,
        const float* __restrict__ B, const float* __restrict__ bias,
        float* __restrict__ C, int M, int N, int K, int act) {
    constexpr int BK = 16;
    __shared__ float As[BK][BM];   // transposed: [k][m]
    __shared__ float Bs[BK][BN];
    const int t  = threadIdx.x;
    const int tx = t % (BN / TN);
    const int ty = t / (BN / TN);
    const int m0 = blockIdx.y * BM;
    const int n0 = blockIdx.x * BN;
    float acc[TM][TN];
    #pragma unroll
    for (int i = 0; i < TM; ++i)
        #pragma unroll
        for (int j = 0; j < TN; ++j) acc[i][j] = 0.f;
    const bool nAligned = ((N & 3) == 0);

    for (int k0 = 0; k0 < K; k0 += BK) {
        // stage A tile (BM x BK), store transposed
        #pragma unroll
        for (int r = 0; r < BM / 64; ++r) {
            int idx = t + r * 256;          // float4 index within tile
            int m   = idx >> 2;
            int k4  = (idx & 3) * 4;
            float4 av = *(const float4*)&A[(size_t)(m0 + m) * K + k0 + k4];
            As[k4 + 0][m] = av.x; As[k4 + 1][m] = av.y;
            As[k4 + 2][m] = av.z; As[k4 + 3][m] = av.w;
        }
        // stage B tile (BK x BN)
        if (nAligned) {
            #pragma unroll
            for (int r = 0; r < (BK * BN) / 1024; ++r) {
                int idx = t + r * 256;
                int k   = idx / (BN / 4);
                int n4  = (idx % (BN / 4)) * 4;
                int gn  = n0 + n4;
                float4 bv = make_float4(0.f, 0.f, 0.f, 0.f);
                const float* bp = &B[(size_t)(k0 + k) * N + gn];
                if (gn + 3 < N) bv = *(const float4*)bp;
                else {
                    if (gn + 0 < N) bv.x = bp[0];
                    if (gn + 1 < N) bv.y = bp[1];
                    if (gn + 2 < N) bv.z = bp[2];
                }
                *(float4*)&Bs[k][n4] = bv;
            }
        } else {
            #pragma unroll
            for (int r = 0; r < (BK * BN) / 256; ++r) {
                int idx = t + r * 256;
                int k   = idx / BN;
                int n   = idx % BN;
                int gn  = n0 + n;
                Bs[k][n] = (gn < N) ? B[(size_t)(k0 + k) * N + gn] : 0.f;
            }
        }
        __syncthreads();
        #pragma unroll
        for (int kk = 0; kk < BK; ++kk) {
            float a[TM], bb[TN];
            #pragma unroll
            for (int i = 0; i < TM / 4; ++i) {
                float4 v = *(const float4*)&As[kk][ty * TM + i * 4];
                a[i*4+0] = v.x; a[i*4+1] = v.y; a[i*4+2] = v.z; a[i*4+3] = v.w;
            }
            #pragma unroll
            for (int j = 0; j < TN / 4; ++j) {
                float4 v = *(const float4*)&Bs[kk][tx * TN + j * 4];
                bb[j*4+0] = v.x; bb[j*4+1] = v.y; bb[j*4+2] = v.z; bb[j*4+3] = v.w;
            }
            #pragma unroll
            for (int i = 0; i < TM; ++i)
                #pragma unroll
                for (int j = 0; j < TN; ++j)
                    acc[i][j] = fmaf(a[i], bb[j], acc[i][j]);
        }
        __syncthreads();
    }
    // epilogue
    #pragma unroll
    for (int i = 0; i < TM; ++i) {
        int gm = m0 + ty * TM + i;
        #pragma unroll
        for (int j = 0; j < TN; ++j) {
            int gn = n0 + tx * TN + j;
            if (gn < N) {
                float v = acc[i][j];
                if (bias) v += bias[gn];
                if (act)  v = gelu_f(v);
                C[(size_t)gm * N + gn] = v;
            }
        }
    }
}

template<int BM, int BN, int TM, int TN>
__global__ void __launch_bounds__(256) gemm_kernel(const float* __restrict__ A,
        const float* __restrict__ B, const float* __restrict__ bias,
        float* __restrict__ C, int M, int N, int K, int act) {
    gemm_body<BM, BN, TM, TN>(A, B, bias, C, M, N, K, act);
}

// batched QKV: blockIdx.z selects weight/output (fills the GPU: 3x blocks)
template<int BM, int BN, int TM, int TN>
__global__ void __launch_bounds__(256) gemm3_kernel(const float* __restrict__ A,
        const float* __restrict__ B0, const float* __restrict__ B1, const float* __restrict__ B2,
        float* __restrict__ C0, float* __restrict__ C1, float* __restrict__ C2,
        int M, int N, int K) {
    const float* B = (blockIdx.z == 0) ? B0 : (blockIdx.z == 1) ? B1 : B2;
    float*       C = (blockIdx.z == 0) ? C0 : (blockIdx.z == 1) ? C1 : C2;
    gemm_body<BM, BN, TM, TN>(A, B, nullptr, C, M, N, K, 0);
}

// ---------------- attention ----------------
// grid (S/16, NH, B), 256 threads. Per block: 16 queries of one (b,h).
// scores materialized in LDS (16x1024), K/V staged in 64-row LDS tiles.
__global__ void __launch_bounds__(256) attn_kernel(const float* __restrict__ qb,
        const float* __restrict__ kb, const float* __restrict__ vb,
        const int* __restrict__ mask, float* __restrict__ ctx) {
    const int qt = blockIdx.x;
    const int h  = blockIdx.y;
    const int b  = blockIdx.z;
    const int t  = threadIdx.x;
    const int q0 = qt * 16;

    __shared__ float sc[16][1028];   // +4 pad keeps float4 rows 16B aligned
    __shared__ float KV[64][68];

    const int qr = t >> 4;   // scores: this thread's query row 0..15
    const int jj = t & 15;

    // Q row in registers, pre-scaled by 1/sqrt(64)
    float qreg[64];
    {
        const float* qp = qb + ((size_t)(b * S_LEN + q0 + qr) * DM + h * DKH);
        #pragma unroll
        for (int i = 0; i < 16; ++i) {
            float4 v = *(const float4*)(qp + i * 4);
            qreg[i*4+0] = v.x * 0.125f; qreg[i*4+1] = v.y * 0.125f;
            qreg[i*4+2] = v.z * 0.125f; qreg[i*4+3] = v.w * 0.125f;
        }
    }

    // ---- scores = (Q/8) @ K^T, masked ----
    for (int kt = 0; kt < S_LEN; kt += 64) {
        __syncthreads();   // protect KV reuse
        {
            int row = t >> 2, seg = t & 3;
            const float* kp = kb + ((size_t)(b * S_LEN + kt + row) * DM + h * DKH + seg * 16);
            float4 v0 = *(const float4*)(kp + 0);
            float4 v1 = *(const float4*)(kp + 4);
            float4 v2 = *(const float4*)(kp + 8);
            float4 v3 = *(const float4*)(kp + 12);
            float* kd = &KV[row][seg * 16];
            *(float4*)(kd + 0) = v0; *(float4*)(kd + 4)  = v1;
            *(float4*)(kd + 8) = v2; *(float4*)(kd + 12) = v3;
        }
        __syncthreads();
        #pragma unroll
        for (int i = 0; i < 4; ++i) {
            int k = jj + i * 16;
            float dot = 0.f;
            #pragma unroll
            for (int d = 0; d < 16; ++d) {
                float4 kv = *(const float4*)&KV[k][d * 4];
                dot += qreg[d*4+0]*kv.x + qreg[d*4+1]*kv.y
                     + qreg[d*4+2]*kv.z + qreg[d*4+3]*kv.w;
            }
            int kg = kt + k;
            if (mask[b * S_LEN + kg] == 0) dot = -1e9f;
            sc[qr][kg] = dot;
        }
    }
    __syncthreads();

    // ---- softmax per row (16 threads/row, width-16 shuffle reduce) ----
    {
        float m = -3.4e38f;
        #pragma unroll
        for (int i = 0; i < 64; ++i) m = fmaxf(m, sc[qr][jj + i * 16]);
        #pragma unroll
        for (int off = 1; off < 16; off <<= 1) m = fmaxf(m, __shfl_xor(m, off, 16));
        float s = 0.f;
        #pragma unroll
        for (int i = 0; i < 64; ++i) {
            float e = __expf(sc[qr][jj + i * 16] - m);
            sc[qr][jj + i * 16] = e;
            s += e;
        }
        #pragma unroll
        for (int off = 1; off < 16; off <<= 1) s += __shfl_xor(s, off, 16);
        float inv = 1.0f / s;
        #pragma unroll
        for (int i = 0; i < 64; ++i) sc[qr][jj + i * 16] *= inv;
    }

    // ---- ctx = P @ V.  wave w owns queries {4w..4w+3}, lane d owns dim d ----
    const int w = t >> 6;
    const int d = t & 63;
    float a0 = 0.f, a1 = 0.f, a2 = 0.f, a3 = 0.f;
    for (int kt = 0; kt < S_LEN; kt += 64) {
        __syncthreads();
        {
            int row = t >> 2, seg = t & 3;
            const float* vp = vb + ((size_t)(b * S_LEN + kt + row) * DM + h * DKH + seg * 16);
            float4 v0 = *(const float4*)(vp + 0);
            float4 v1 = *(const float4*)(vp + 4);
            float4 v2 = *(const float4*)(vp + 8);
            float4 v3 = *(const float4*)(vp + 12);
            float* vd = &KV[row][seg * 16];
            *(float4*)(vd + 0) = v0; *(float4*)(vd + 4)  = v1;
            *(float4*)(vd + 8) = v2; *(float4*)(vd + 12) = v3;
        }
        __syncthreads();
        #pragma unroll
        for (int kk = 0; kk < 64; kk += 4) {
            float v0 = KV[kk+0][d], v1 = KV[kk+1][d], v2 = KV[kk+2][d], v3 = KV[kk+3][d];
            float4 p;
            p = *(const float4*)&sc[w*4+0][kt+kk]; a0 += p.x*v0 + p.y*v1 + p.z*v2 + p.w*v3;
            p = *(const float4*)&sc[w*4+1][kt+kk]; a1 += p.x*v0 + p.y*v1 + p.z*v2 + p.w*v3;
            p = *(const float4*)&sc[w*4+2][kt+kk]; a2 += p.x*v0 + p.y*v1 + p.z*v2 + p.w*v3;
            p = *(const float4*)&sc[w*4+3][kt+kk]; a3 += p.x*v0 + p.y*v1 + p.z*v2 + p.w*v3;
        }
    }
    size_t obase = (size_t)(b * S_LEN + q0 + w * 4) * DM + h * DKH + d;
    ctx[obase + 0 * DM] = a0;
    ctx[obase + 1 * DM] = a1;
    ctx[obase + 2 * DM] = a2;
    ctx[obase + 3 * DM] = a3;
}

// ---------------- fused residual-add + LayerNorm (in place on x) ----------------
__global__ void __launch_bounds__(256) ln_kernel(float* __restrict__ x,
        const float* __restrict__ res, const float* __restrict__ g,
        const float* __restrict__ b) {
    const int row = blockIdx.x;
    const int t   = threadIdx.x;
    const size_t base = (size_t)row * DM;
    float v[3];
    #pragma unroll
    for (int i = 0; i < 3; ++i) {
        int c = t + i * 256;
        v[i] = x[base + c] + (res ? res[base + c] : 0.f);
    }
    float s  = v[0] + v[1] + v[2];
    float s2 = v[0]*v[0] + v[1]*v[1] + v[2]*v[2];
    #pragma unroll
    for (int off = 1; off < 64; off <<= 1) {
        s  += __shfl_xor(s,  off);
        s2 += __shfl_xor(s2, off);
    }
    __shared__ float red[8];
    int w = t >> 6;
    if ((t & 63) == 0) { red[w] = s; red[w + 4] = s2; }
    __syncthreads();
    s  = red[0] + red[1] + red[2] + red[3];
    s2 = red[4] + red[5] + red[6] + red[7];
    const float mean = s * (1.0f / DM);
    const float var  = s2 * (1.0f / DM) - mean * mean;
    const float rstd = rsqrtf(var + 1e-5f);
    #pragma unroll
    for (int i = 0; i < 3; ++i) {
        int c = t + i * 256;
        x[base + c] = (v[i] - mean) * rstd * g[c] + b[c];
    }
}

// ---------------- driver ----------------
extern "C" void kernel_launch(void* const* d_in, const int* in_sizes, int n_in,
                              void* d_out, int out_size, void* d_ws, size_t ws_size,
                              hipStream_t stream) {
    (void)in_sizes; (void)n_in; (void)out_size; (void)ws_size;
    const int*   ids  = (const int*)  d_in[0];
    const int*   amsk = (const int*)  d_in[1];
    const float* tok  = (const float*)d_in[2];
    const float* pe   = (const float*)d_in[3];
    const float* Wq   = (const float*)d_in[4];
    const float* Wk   = (const float*)d_in[5];
    const float* Wv   = (const float*)d_in[6];
    const float* Wo   = (const float*)d_in[7];
    const float* ln1g = (const float*)d_in[8];
    const float* ln1b = (const float*)d_in[9];
    const float* ln2g = (const float*)d_in[10];
    const float* ln2b = (const float*)d_in[11];
    const float* W1   = (const float*)d_in[12];
    const float* b1   = (const float*)d_in[13];
    const float* W2   = (const float*)d_in[14];
    const float* b2   = (const float*)d_in[15];
    const float* lnfg = (const float*)d_in[16];
    const float* lnfb = (const float*)d_in[17];
    const float* Wout = (const float*)d_in[18];
    const float* bout = (const float*)d_in[19];
    float* out = (float*)d_out;

    float* ws = (float*)d_ws;
    const size_t CH = (size_t)NT * DM;
    float* x  = ws;
    float* qb = ws + 1 * CH;
    float* kb = ws + 2 * CH;
    float* vb = ws + 3 * CH;
    float* cx = ws + 4 * CH;
    float* tm = ws + 5 * CH;
    float* hb = ws + 6 * CH;   // NT x FF

    embed_kernel<<<NT * DM / 256, 256, 0, stream>>>(ids, tok, pe, x);

    const size_t DD = (size_t)DM * DM;
    for (int l = 0; l < NL; ++l) {
        gemm3_kernel<64,64,4,4><<<dim3(DM/64, NT/64, 3), 256, 0, stream>>>(
            x, Wq + l*DD, Wk + l*DD, Wv + l*DD, qb, kb, vb, NT, DM, DM);
        attn_kernel<<<dim3(S_LEN/16, NH, 2), 256, 0, stream>>>(qb, kb, vb, amsk, cx);
        gemm_kernel<64,64,4,4><<<dim3(DM/64, NT/64), 256, 0, stream>>>(
            cx, Wo + l*DD, nullptr, tm, NT, DM, DM, 0);
        ln_kernel<<<NT, 256, 0, stream>>>(x, tm, ln1g + l*DM, ln1b + l*DM);
        gemm_kernel<64,128,4,8><<<dim3(FF/128, NT/64), 256, 0, stream>>>(
            x, W1 + (size_t)l*DM*FF, b1 + (size_t)l*FF, hb, NT, FF, DM, 1);
        gemm_kernel<64,64,4,4><<<dim3(DM/64, NT/64), 256, 0, stream>>>(
            hb, W2 + (size_t)l*FF*DM, b2 + (size_t)l*DM, tm, NT, DM, FF, 0);
        ln_kernel<<<NT, 256, 0, stream>>>(x, tm, ln2g + l*DM, ln2b + l*DM);
    }
    ln_kernel<<<NT, 256, 0, stream>>>(x, nullptr, lnfg, lnfb);
    gemm_kernel<64,128,4,8><<<dim3((VOC + 127)/128, NT/64), 256, 0, stream>>>(
        x, Wout, bout, out, NT, VOC, DM, 0);
}